// Round 12
// baseline (55.618 us; speedup 1.0000x reference)
//
#include <hip/hip_runtime.h>

// Problem constants (B, C, O, K, H, W) = (8, 64, 64, 3, 128, 128)
#define NTAP 9
#define C_DIM 64
#define O_DIM 64
#define HW 128
#define HP 130   // padded spatial extent (one halo pixel each side)

typedef short s16x8 __attribute__((ext_vector_type(8)));
typedef float f32x16 __attribute__((ext_vector_type(16)));

__device__ __forceinline__ unsigned short f2bf(float x) {
    unsigned int u = __float_as_uint(x);
    unsigned int r = (u + 0x7fffu + ((u >> 16) & 1u)) >> 16;
    return (unsigned short)r;
}

// ---------------------------------------------------------------------------
// Prep kernel (fused):
//  blocks [0, 8*HP):      feat [8][64][128][128] f32 -> featT [8][130][130][64]
//                         bf16 channel-last with zero-padded halo ring.
//  blocks [8*HP, +144):   W [64][3][3][64] f32 -> fragment-major bf16 Wf.
//    Fragment F = ((tap*4 + s)*2 + m)*64 + lane, element e:
//      c = 16*s + 8*(lane>>5) + e,   o = 32*m + (lane&31)
//    featT puts c at natural channel-last position, so a B-fragment for
//    (s,g) is the 16B at pixel offset s*32+g*16 -- same (lane>>5,e)->k-slot
//    mapping as Wf: contraction correct under any HW k-slot permutation.
// ---------------------------------------------------------------------------
__global__ __launch_bounds__(256) void prep_kernel(
    const float* __restrict__ feat, const float* __restrict__ W,
    unsigned short* __restrict__ featT, unsigned short* __restrict__ Wf)
{
    const int bid = blockIdx.x;
    const int tid = threadIdx.x;

    if (bid >= 8 * HP) {                       // ---- W swizzle part ----
        int idx = (bid - 8 * HP) * 256 + tid;
        if (idx >= NTAP * 4 * 2 * 64 * 8) return;
        int e    = idx & 7;
        int lane = (idx >> 3) & 63;
        int m    = (idx >> 9) & 1;
        int s    = (idx >> 10) & 3;
        int tap  = idx >> 12;
        int c = s * 16 + ((lane >> 5) << 3) + e;
        int o = (m << 5) + (lane & 31);
        Wf[idx] = f2bf(W[c * 576 + tap * 64 + o]);
        return;
    }

    // ---- feat transpose part: one block per (b, padded row hp) ----
    __shared__ unsigned short lds_t[C_DIM][134];   // [c][w], odd-dword stride

    const int b   = bid & 7;                   // XCD x owns batch x
    const int hp  = bid >> 3;                  // 0..129
    const int hr  = hp - 1;
    const bool rowv = (hr >= 0) && (hr < HW);

    if (rowv) {
        const int wq = tid & 31;               // w = 4*wq (coalesced)
        const int c0 = tid >> 5;               // c = c0 + 8*i
        #pragma unroll
        for (int i = 0; i < 8; ++i) {
            const int c = c0 + 8 * i;
            float4 v = *(const float4*)&feat[(((size_t)(b * C_DIM + c)) * HW + hr) * HW + 4 * wq];
            unsigned int lo = (unsigned int)f2bf(v.x) | ((unsigned int)f2bf(v.y) << 16);
            unsigned int hi = (unsigned int)f2bf(v.z) | ((unsigned int)f2bf(v.w) << 16);
            *(unsigned int*)&lds_t[c][4 * wq]     = lo;
            *(unsigned int*)&lds_t[c][4 * wq + 2] = hi;
        }
    }
    __syncthreads();

    for (int u = tid; u < HP * 8; u += 256) {  // 1040 units = 130 wp x 8 octets
        const int wp  = u >> 3;
        const int oct = u & 7;
        s16x8 pk = {0, 0, 0, 0, 0, 0, 0, 0};
        if (rowv && wp >= 1 && wp <= HW) {
            #pragma unroll
            for (int e = 0; e < 8; ++e) pk[e] = (short)lds_t[oct * 8 + e][wp - 1];
        }
        *(s16x8*)&featT[((((size_t)b * HP) + hp) * HP + wp) * 64 + oct * 8] = pk;
    }
}

// ---------------------------------------------------------------------------
// Main kernel: NO LDS, NO barrier. One block per (batch, h-PAIR, 64-w half);
// 256 threads = 4 fully-independent waves (m = o-half, pg = w-32-group).
// Each wave: TWO 32px x 32o chains (rows h0, h0+1) sharing every A-fragment.
// B-fragments are single 16B loads from featT (XCD-local L2-resident; block's
// 4 waves share one 3x66-pixel window -> L1/L2 line reuse).
// out[o][px] = sum_tap tm[tap][px] * (W_tap^T . featT[px + shift])
// ---------------------------------------------------------------------------
__global__ __launch_bounds__(256, 4) void dyconv_kernel(
    const unsigned short* __restrict__ featT, const float* __restrict__ tm,
    const unsigned short* __restrict__ Wf, float* __restrict__ out)
{
    const int flat  = blockIdx.x;              // 0..1023, XCD x owns batch x
    const int b     = flat & 7;
    const int inner = flat >> 3;               // 0..127
    const int h0    = (inner >> 1) * 2;        // 0,2,..,126
    const int w0    = (inner & 1) << 6;        // 0 or 64

    const int tid  = threadIdx.x;
    const int lane = tid & 63;
    const int wave = tid >> 6;                 // 0..3
    const int m    = wave >> 1;                // o-half
    const int pg   = wave & 1;                 // w 32-group
    const int g    = lane >> 5;                // k-slot half
    const int c31  = lane & 31;
    const int wout = w0 + pg * 32 + c31;       // pixel w (D col = lane&31)

    const s16x8* __restrict__ Wf8 = (const s16x8*)Wf;

    f32x16 acc0 = {0,0,0,0,0,0,0,0,0,0,0,0,0,0,0,0};
    f32x16 acc1 = acc0;

    __builtin_amdgcn_s_setprio(1);
    #pragma unroll
    for (int tap = 0; tap < NTAP; ++tap) {
        const int di = tap / 3;
        const int dj = tap % 3;
        // padded pixel (hp, wp) = (h0 + di, wout + dj); rows h0 / h0+1 chains
        const unsigned short* bp0 =
            featT + ((((size_t)b * HP) + h0 + di) * HP + wout + dj) * 64 + g * 8;
        const unsigned short* bp1 = bp0 + (size_t)HP * 64;
        const float* tp = tm + ((size_t)(b * NTAP + tap)) * (HW * HW)
                        + (size_t)h0 * HW + wout;
        const float tv0 = tp[0];
        const float tv1 = tp[HW];

        f32x16 pa0 = {0,0,0,0,0,0,0,0,0,0,0,0,0,0,0,0};
        f32x16 pa1 = pa0;
        #pragma unroll
        for (int s = 0; s < 4; ++s) {
            s16x8 a   = Wf8[((tap * 4 + s) * 2 + m) * 64 + lane];  // shared A
            s16x8 bf0 = *(const s16x8*)(bp0 + s * 16);             // 16B L2 hit
            s16x8 bf1 = *(const s16x8*)(bp1 + s * 16);
            pa0 = __builtin_amdgcn_mfma_f32_32x32x16_bf16(a, bf0, pa0, 0, 0, 0);
            pa1 = __builtin_amdgcn_mfma_f32_32x32x16_bf16(a, bf1, pa1, 0, 0, 0);
        }
        #pragma unroll
        for (int r = 0; r < 16; ++r) {
            acc0[r] = fmaf(tv0, pa0[r], acc0[r]);
            acc1[r] = fmaf(tv1, pa1[r], acc1[r]);
        }
    }
    __builtin_amdgcn_s_setprio(0);

    // ---- store rows h0, h0+1: D (32x32): col = c31, o = (r&3)+8*(r>>2)+4g+32m
    float* op = out + ((size_t)b * O_DIM) * (HW * HW) + (size_t)h0 * HW + wout;
    #pragma unroll
    for (int r = 0; r < 16; ++r) {
        const int o = (r & 3) + ((r >> 2) << 3) + (g << 2) + (m << 5);
        op[(size_t)o * (HW * HW)]      = acc0[r];
        op[(size_t)o * (HW * HW) + HW] = acc1[r];
    }
}

extern "C" void kernel_launch(void* const* d_in, const int* in_sizes, int n_in,
                              void* d_out, int out_size, void* d_ws, size_t ws_size,
                              hipStream_t stream) {
    const float* feat = (const float*)d_in[0];   // [8,64,128,128] f32
    const float* tm   = (const float*)d_in[1];   // [8,9,16384]    f32
    const float* W    = (const float*)d_in[2];   // [64,3,3,64]    f32
    float* out        = (float*)d_out;           // [8,64,128,128] f32

    // ws layout: featT [0, 17305600) bf16; Wf [17305600, +73728)
    unsigned short* featT = (unsigned short*)d_ws;
    unsigned short* Wf    = (unsigned short*)((char*)d_ws + 17305600);

    prep_kernel<<<dim3(8 * HP + 144), dim3(256), 0, stream>>>(feat, W, featT, Wf);
    dyconv_kernel<<<dim3(1024), dim3(256), 0, stream>>>(featT, tm, Wf, out);
}

// Round 13
// 42.564 us; speedup vs baseline: 1.3067x; 1.3067x over previous
//
#include <hip/hip_runtime.h>

// Problem constants (B, C, O, K, H, W) = (8, 64, 64, 3, 128, 128)
#define NTAP 9
#define C_DIM 64
#define O_DIM 64
#define HW 128

typedef short s16x8 __attribute__((ext_vector_type(8)));
typedef float f32x16 __attribute__((ext_vector_type(16)));

__device__ __forceinline__ unsigned short f2bf(float x) {
    unsigned int u = __float_as_uint(x);
    unsigned int r = (u + 0x7fffu + ((u >> 16) & 1u)) >> 16;
    return (unsigned short)r;
}

// pack two f32 -> two bf16 (RNE) in one VALU instruction
__device__ __forceinline__ unsigned int cvt_pk_bf16(float lo, float hi) {
    unsigned int r;
    asm("v_cvt_pk_bf16_f32 %0, %1, %2" : "=v"(r) : "v"(lo), "v"(hi));
    return r;
}

// ---------------------------------------------------------------------------
// Pre-kernel: W [C=64][3][3][O=64] f32 -> fragment-major bf16 (d_ws, 72KB).
// Fragment F = ((tap*4 + s)*2 + m)*64 + lane, element e:
//   c = 16*s + 8*(lane>>5) + e,   o = 32*m + (lane&31)
// Same (lane>>5, e) -> k-slot mapping is used for the feat (B) operand, so the
// contraction is correct under any hardware k-slot permutation.
// ---------------------------------------------------------------------------
__global__ void swizzle_W_kernel(const float* __restrict__ W,
                                 unsigned short* __restrict__ Wf) {
    int idx = blockIdx.x * 256 + threadIdx.x;
    if (idx >= NTAP * 4 * 2 * 64 * 8) return;
    int e    = idx & 7;
    int lane = (idx >> 3) & 63;
    int m    = (idx >> 9) & 1;
    int s    = (idx >> 10) & 3;
    int tap  = idx >> 12;
    int c = s * 16 + ((lane >> 5) << 3) + e;
    int o = (m << 5) + (lane & 31);
    Wf[idx] = f2bf(W[c * 576 + tap * 64 + o]);
}

// ---------------------------------------------------------------------------
// Main kernel: OCCUPANCY-FIRST. One block per (batch, row h, 32-w quarter).
// 128 threads = 2 waves; LDS window 3 x 34 x 64c bf16 = 13056 B.
// -> 12 blocks/CU by LDS, 24 waves/CU (75%) with VGPR <= 84 (launch_bounds).
// Latency hiding comes from TLP (many small blocks at drifting phases), not
// from in-block pipelining (R7/R9/R10 showed that always loses).
// Octet-XOR LDS layout: c-octet `oct` of column wi at 16B slot oct^(wi&7);
// both ds_write_b128 and ds_read_b128 are <=2-way per 16-lane phase (free).
// Wave m (= o-half): ONE 32px x 32o chain, 36 MFMA, per-tap tm fold.
// ---------------------------------------------------------------------------
__global__ __launch_bounds__(128, 6) void dyconv_kernel(
    const float* __restrict__ feat, const float* __restrict__ tm,
    const unsigned short* __restrict__ Wf, float* __restrict__ out)
{
    __shared__ __align__(16) unsigned short feat_lds[3][34][64];  // 13056 B

    // bijective XCD swizzle: XCD x owns batch x; w-quarters adjacent in time
    const int flat  = blockIdx.x;              // 0..4095
    const int b     = flat & 7;
    const int inner = flat >> 3;               // 0..511
    const int h     = inner >> 2;              // 0..127
    const int w0    = (inner & 3) << 5;        // 0,32,64,96

    const int tid  = threadIdx.x;              // 0..127
    const int lane = tid & 63;
    const int m    = tid >> 6;                 // wave = o-half
    const int g    = lane >> 5;                // k-slot half
    const int c31  = lane & 31;
    const int wout = w0 + c31;                 // pixel w (D col = lane&31)

    // ---- staging: 240 units = 3 rows x 10 w-quads x 8 c-octets ----
    // unit: 8 coalesced float4 loads (one c-octet, 4 w) -> cvt_pk -> <=4 b128
    auto do_unit = [&](int U) {
        const int oct = U & 7;
        const int t3  = U >> 3;                // 0..29
        const int q   = t3 % 10;               // w-quad: wb = w0-4+4q
        const int r   = t3 / 10;               // input row (hr = h-1+r)
        const int hr  = h - 1 + r;
        const int wb  = w0 - 4 + 4 * q;
        const bool ld = (hr >= 0) && (hr < HW) && (wb >= 0) && (wb <= HW - 4);
        const float* src = feat + (((size_t)(b * C_DIM + oct * 8)) * HW + hr) * HW + wb;
        float4 v[8];
        #pragma unroll
        for (int j = 0; j < 8; ++j)
            v[j] = ld ? *(const float4*)(src + (size_t)j * (HW * HW))
                      : float4{0.f, 0.f, 0.f, 0.f};
        #pragma unroll
        for (int i = 0; i < 4; ++i) {
            const int wi = 4 * q - 3 + i;      // window index = w_in - (w0-1)
            if (wi >= 0 && wi <= 33) {
                const int slot = oct ^ (wi & 7);
                int4 pk;
                pk.x = cvt_pk_bf16(((const float*)&v[0])[i], ((const float*)&v[1])[i]);
                pk.y = cvt_pk_bf16(((const float*)&v[2])[i], ((const float*)&v[3])[i]);
                pk.z = cvt_pk_bf16(((const float*)&v[4])[i], ((const float*)&v[5])[i]);
                pk.w = cvt_pk_bf16(((const float*)&v[6])[i], ((const float*)&v[7])[i]);
                *(int4*)&feat_lds[r][wi][slot * 8] = pk;
            }
        }
    };

    // tm prefetch first (VMEM in flight under staging)
    float tmr[NTAP];
    #pragma unroll
    for (int t = 0; t < NTAP; ++t)
        tmr[t] = tm[((size_t)(b * NTAP + t)) * (HW * HW) + (size_t)h * HW + wout];

    do_unit(tid);                               // units 0..127
    if (tid < 112) do_unit(tid + 128);          // units 128..239

    __syncthreads();

    const s16x8* __restrict__ wbase = (const s16x8*)Wf + (size_t)m * 64 + lane;

    f32x16 acc = {0,0,0,0,0,0,0,0,0,0,0,0,0,0,0,0};

    __builtin_amdgcn_s_setprio(1);
    #pragma unroll
    for (int tap = 0; tap < NTAP; ++tap) {
        const int di = tap / 3;
        const int dj = tap % 3;
        const int wi = c31 + dj;               // 0..33, contiguous across lanes
        const int sw = wi & 7;
        f32x16 pa = {0,0,0,0,0,0,0,0,0,0,0,0,0,0,0,0};
        #pragma unroll
        for (int s = 0; s < 4; ++s) {
            const int slot = (2 * s + g) ^ sw;
            s16x8 bf = *(const s16x8*)&feat_lds[di][wi][slot * 8];
            s16x8 a  = wbase[(tap * 4 + s) * 128];   // L1-hot 16B
            pa = __builtin_amdgcn_mfma_f32_32x32x16_bf16(a, bf, pa, 0, 0, 0);
        }
        const float tv = tmr[tap];
        #pragma unroll
        for (int r = 0; r < 16; ++r)
            acc[r] = fmaf(tv, pa[r], acc[r]);
    }
    __builtin_amdgcn_s_setprio(0);

    // ---- store: D (32x32): col = c31 (pixel), o = (r&3)+8*(r>>2)+4*g+32*m ----
    float* op = out + ((size_t)b * O_DIM) * (HW * HW) + (size_t)h * HW + wout;
    #pragma unroll
    for (int r = 0; r < 16; ++r) {
        const int o = (r & 3) + ((r >> 2) << 3) + (g << 2) + (m << 5);
        op[(size_t)o * (HW * HW)] = acc[r];
    }
}

extern "C" void kernel_launch(void* const* d_in, const int* in_sizes, int n_in,
                              void* d_out, int out_size, void* d_ws, size_t ws_size,
                              hipStream_t stream) {
    const float* feat = (const float*)d_in[0];   // [8,64,128,128] f32
    const float* tm   = (const float*)d_in[1];   // [8,9,16384]    f32
    const float* W    = (const float*)d_in[2];   // [64,3,3,64]    f32
    float* out        = (float*)d_out;           // [8,64,128,128] f32
    unsigned short* Wf = (unsigned short*)d_ws;  // 73728 B scratch

    swizzle_W_kernel<<<dim3(144), dim3(256), 0, stream>>>(W, Wf);
    dyconv_kernel<<<dim3(4096), dim3(128), 0, stream>>>(feat, tm, Wf, out);
}

// Round 14
// 38.531 us; speedup vs baseline: 1.4435x; 1.1047x over previous
//
#include <hip/hip_runtime.h>

// Problem constants (B, C, O, K, H, W) = (8, 64, 64, 3, 128, 128)
#define NTAP 9
#define C_DIM 64
#define O_DIM 64
#define HW 128

typedef short s16x8 __attribute__((ext_vector_type(8)));
typedef float f32x16 __attribute__((ext_vector_type(16)));

__device__ __forceinline__ unsigned short f2bf(float x) {
    unsigned int u = __float_as_uint(x);
    unsigned int r = (u + 0x7fffu + ((u >> 16) & 1u)) >> 16;
    return (unsigned short)r;
}

// ---------------------------------------------------------------------------
// Pre-kernel: W [C=64][3][3][O=64] f32 -> fragment-major bf16 (d_ws, 72KB).
// Fragment F = ((tap*4 + s)*2 + m)*64 + lane, element e:
//   c = 16*s + 8*(lane>>5) + e,   o = 32*m + (lane&31)
// Same (lane>>5, e) -> k-slot mapping is used for the feat (B) operand, so the
// contraction is correct under any hardware k-slot permutation.
// ---------------------------------------------------------------------------
__global__ void swizzle_W_kernel(const float* __restrict__ W,
                                 unsigned short* __restrict__ Wf) {
    int idx = blockIdx.x * 256 + threadIdx.x;
    if (idx >= NTAP * 4 * 2 * 64 * 8) return;
    int e    = idx & 7;
    int lane = (idx >> 3) & 63;
    int m    = (idx >> 9) & 1;
    int s    = (idx >> 10) & 3;
    int tap  = idx >> 12;
    int c = s * 16 + ((lane >> 5) << 3) + e;
    int o = (m << 5) + (lane & 31);
    Wf[idx] = f2bf(W[c * 576 + tap * 64 + o]);
}

// ---------------------------------------------------------------------------
// Main kernel: R8-champion structure. One block per (batch, row h, 64-w half),
// 256 threads = 4 waves, grid 2048.
// LDS window: 3 rows x 66 wi x 64 c bf16, TIGHT 128B rows (25344 B -> 6
// blocks/CU), octet-XOR layout keyed on (wi>>3):
//   c-octet `oct` of column wi lives at 16B slot  oct ^ ((wi>>3)&7).
// Read lanes {c31, c31+8, +16, +24} share wi&7 but differ in (wi>>3)&7 ->
// distinct bank quads -> conflict-free b128 reads; writes alias <=2-way (free).
// Wave (m = o-half, pg = w-32-group): ONE 32px x 32o chain, 36 MFMA, tm fold.
// ---------------------------------------------------------------------------
__global__ __launch_bounds__(256, 6) void dyconv_kernel(
    const float* __restrict__ feat, const float* __restrict__ tm,
    const unsigned short* __restrict__ Wf, float* __restrict__ out)
{
    __shared__ __align__(16) unsigned short feat_lds[3][66][64];  // 25344 B

    // bijective XCD swizzle: XCD x owns batch x; h/w neighbors adjacent in time
    const int flat  = blockIdx.x;              // 0..2047
    const int b     = flat & 7;
    const int inner = flat >> 3;               // 0..255
    const int h     = inner >> 1;              // 0..127
    const int w0    = (inner & 1) << 6;        // 0 or 64

    const int tid  = threadIdx.x;
    const int lane = tid & 63;
    const int wave = tid >> 6;                 // 0..3
    const int m    = wave >> 1;                // o-half
    const int pg   = wave & 1;                 // w 32-group
    const int g    = lane >> 5;                // k-slot half
    const int c31  = lane & 31;
    const int pw   = pg * 32 + c31;            // pixel w-offset 0..63
    const int wout = w0 + pw;

    // ---- stage rows h-1..h+1, w-span [w0-4, w0+68) x 64 c (halos included) ----
    // unit U = ((r*18)+q)*8 + oct: 8 coalesced float4 loads (4w x 8c), pack,
    // <=4 ds_write_b128 at XOR'd slots. Threads 0..175 do 2 units, rest 1.
    for (int U = tid; U < 432; U += 256) {
        const int oct = U & 7;
        const int t6  = U >> 3;                // 0..53
        const int q   = t6 % 18;               // w-quad: wb = w0-4+4q
        const int r   = t6 / 18;               // input row (hr = h-1+r)
        const int hr  = h - 1 + r;
        const int wb  = w0 - 4 + 4 * q;
        const bool ld = (hr >= 0) && (hr < HW) && (wb >= 0) && (wb <= HW - 4);
        const float* src = feat + (((size_t)(b * C_DIM + oct * 8)) * HW + hr) * HW + wb;
        float4 v[8];
        #pragma unroll
        for (int j = 0; j < 8; ++j)
            v[j] = ld ? *(const float4*)(src + (size_t)j * (HW * HW))
                      : float4{0.f, 0.f, 0.f, 0.f};
        #pragma unroll
        for (int i = 0; i < 4; ++i) {
            const int wi = 4 * q - 3 + i;      // window index = w_in - (w0-1)
            if (wi >= 0 && wi <= 65) {
                const int slot = oct ^ ((wi >> 3) & 7);
                s16x8 pk;
                #pragma unroll
                for (int j = 0; j < 8; ++j) {
                    const float* vf = (const float*)&v[j];
                    pk[j] = (short)f2bf(vf[i]);
                }
                *(s16x8*)&feat_lds[r][wi][slot * 8] = pk;
            }
        }
    }

    // tm prefetch (independent of LDS; in flight across the barrier)
    float tmr[NTAP];
    #pragma unroll
    for (int t = 0; t < NTAP; ++t)
        tmr[t] = tm[((size_t)(b * NTAP + t)) * (HW * HW) + (size_t)h * HW + wout];

    __syncthreads();

    const s16x8* __restrict__ Wf8 = (const s16x8*)Wf;

    f32x16 acc = {0,0,0,0,0,0,0,0,0,0,0,0,0,0,0,0};

    __builtin_amdgcn_s_setprio(1);
    #pragma unroll
    for (int tap = 0; tap < NTAP; ++tap) {
        const int di = tap / 3;
        const int dj = tap % 3;
        const int wi = pw + dj;                // 0..65, contiguous across lanes
        const int key = (wi >> 3) & 7;
        f32x16 pa = {0,0,0,0,0,0,0,0,0,0,0,0,0,0,0,0};
        #pragma unroll
        for (int s = 0; s < 4; ++s) {
            const int slot = (2 * s + g) ^ key;
            s16x8 bf = *(const s16x8*)&feat_lds[di][wi][slot * 8];
            s16x8 a  = Wf8[((tap * 4 + s) * 2 + m) * 64 + lane];   // L1/L2-hot
            pa = __builtin_amdgcn_mfma_f32_32x32x16_bf16(a, bf, pa, 0, 0, 0);
        }
        const float tv = tmr[tap];
        #pragma unroll
        for (int r = 0; r < 16; ++r)
            acc[r] = fmaf(tv, pa[r], acc[r]);
    }
    __builtin_amdgcn_s_setprio(0);

    // ---- store: D (32x32): col = c31 (pixel), o = (r&3)+8*(r>>2)+4*g+32*m ----
    float* op = out + ((size_t)b * O_DIM) * (HW * HW) + (size_t)h * HW + wout;
    #pragma unroll
    for (int r = 0; r < 16; ++r) {
        const int o = (r & 3) + ((r >> 2) << 3) + (g << 2) + (m << 5);
        op[(size_t)o * (HW * HW)] = acc[r];
    }
}

extern "C" void kernel_launch(void* const* d_in, const int* in_sizes, int n_in,
                              void* d_out, int out_size, void* d_ws, size_t ws_size,
                              hipStream_t stream) {
    const float* feat = (const float*)d_in[0];   // [8,64,128,128] f32
    const float* tm   = (const float*)d_in[1];   // [8,9,16384]    f32
    const float* W    = (const float*)d_in[2];   // [64,3,3,64]    f32
    float* out        = (float*)d_out;           // [8,64,128,128] f32
    unsigned short* Wf = (unsigned short*)d_ws;  // 73728 B scratch

    swizzle_W_kernel<<<dim3(144), dim3(256), 0, stream>>>(W, Wf);
    dyconv_kernel<<<dim3(2048), dim3(256), 0, stream>>>(feat, tm, Wf, out);
}

// Round 15
// 36.804 us; speedup vs baseline: 1.5112x; 1.0469x over previous
//
#include <hip/hip_runtime.h>

// Problem constants (B, C, O, K, H, W) = (8, 64, 64, 3, 128, 128)
#define NTAP 9
#define C_DIM 64
#define O_DIM 64
#define HW 128
#define CPAD 72   // R8-champion LDS row stride (144B): 16B-aligned, mild 4-way

typedef short s16x8 __attribute__((ext_vector_type(8)));
typedef float f32x16 __attribute__((ext_vector_type(16)));

__device__ __forceinline__ unsigned short f2bf(float x) {
    unsigned int u = __float_as_uint(x);
    unsigned int r = (u + 0x7fffu + ((u >> 16) & 1u)) >> 16;
    return (unsigned short)r;
}

// ---------------------------------------------------------------------------
// Pre-kernel: W [C=64][3][3][O=64] f32 -> fragment-major bf16 (d_ws, 72KB).
// Fragment F = ((tap*4 + s)*2 + m)*64 + lane, element e:
//   c = 16*s + 8*(lane>>5) + e,   o = 32*m + (lane&31)
// Same (lane>>5, e) -> k-slot mapping is used for the feat (B) operand, so the
// contraction is correct under any hardware k-slot permutation.
// ---------------------------------------------------------------------------
__global__ void swizzle_W_kernel(const float* __restrict__ W,
                                 unsigned short* __restrict__ Wf) {
    int idx = blockIdx.x * 256 + threadIdx.x;
    if (idx >= NTAP * 4 * 2 * 64 * 8) return;
    int e    = idx & 7;
    int lane = (idx >> 3) & 63;
    int m    = (idx >> 9) & 1;
    int s    = (idx >> 10) & 3;
    int tap  = idx >> 12;
    int c = s * 16 + ((lane >> 5) << 3) + e;
    int o = (m << 5) + (lane & 31);
    Wf[idx] = f2bf(W[c * 576 + tap * 64 + o]);
}

// ---------------------------------------------------------------------------
// Main kernel: EXACT R8-champion structure (31.1us): one block per
// (batch, row h, 64-w half), 256 threads = 4 waves, grid 2048,
// LDS [3][66][72] bf16 (28.5KB), launch_bounds(256,4) -> VGPR cap 128.
// SINGLE delta vs R8: the two staging units per thread load into SEPARATE
// register sets issued back-to-back (one vmcnt group, one round-trip)
// instead of a rolled loop that serializes round-trips through v[8] reuse.
// Wave (m = o-half, pg = w-32-group): ONE 32px x 32o chain, 36 MFMA, tm fold.
// ---------------------------------------------------------------------------
__global__ __launch_bounds__(256, 4) void dyconv_kernel(
    const float* __restrict__ feat, const float* __restrict__ tm,
    const unsigned short* __restrict__ Wf, float* __restrict__ out)
{
    __shared__ __align__(16) unsigned short feat_lds[3][66][CPAD];

    // bijective XCD swizzle: XCD x owns batch x; h/w neighbors adjacent in time
    const int flat  = blockIdx.x;              // 0..2047
    const int b     = flat & 7;
    const int inner = flat >> 3;               // 0..255
    const int h     = inner >> 1;              // 0..127
    const int w0    = (inner & 1) << 6;        // 0 or 64

    const int tid  = threadIdx.x;
    const int lane = tid & 63;
    const int wave = tid >> 6;                 // 0..3
    const int m    = wave >> 1;                // o-half
    const int pg   = wave & 1;                 // w 32-group
    const int g    = lane >> 5;                // k-slot half
    const int c31  = lane & 31;
    const int pw   = pg * 32 + c31;            // pixel w-offset 0..63
    const int wout = w0 + pw;

    // ---- stage rows h-1..h+1, w-span [w0-4, w0+68) x 64 c ----
    // unit U = ((r*18)+q)*8 + oct: 8 coalesced float4 loads (4w x 8c).
    // 432 units. Thread: unit A = tid; unit B = tid+256 (tid<176 only).
    // BOTH units' 16 loads issue before any pack -> one latency round-trip.
    {
        const int octA = tid & 7;
        const int t6A  = tid >> 3;             // 0..31
        const int qA   = t6A % 18;
        const int rA   = t6A / 18;             // 0 or 1
        const int hrA  = h - 1 + rA;
        const int wbA  = w0 - 4 + 4 * qA;
        const bool ldA = (hrA >= 0) && (hrA < HW) && (wbA >= 0) && (wbA <= HW - 4);
        const float* srcA = feat + (((size_t)(b * C_DIM + octA * 8)) * HW + hrA) * HW + wbA;

        const bool hasB = tid < 176;           // units 256..431
        const int UB   = tid + 256;
        const int octB = UB & 7;
        const int t6B  = UB >> 3;              // 32..53
        const int qB   = t6B % 18;
        const int rB   = t6B / 18;             // 1 or 2
        const int hrB  = h - 1 + rB;
        const int wbB  = w0 - 4 + 4 * qB;
        const bool ldB = hasB && (hrB >= 0) && (hrB < HW) && (wbB >= 0) && (wbB <= HW - 4);
        const float* srcB = feat + (((size_t)(b * C_DIM + octB * 8)) * HW + hrB) * HW + wbB;

        float4 va[8], vb[8];
        #pragma unroll
        for (int j = 0; j < 8; ++j)
            va[j] = ldA ? *(const float4*)(srcA + (size_t)j * (HW * HW))
                        : float4{0.f, 0.f, 0.f, 0.f};
        #pragma unroll
        for (int j = 0; j < 8; ++j)
            vb[j] = ldB ? *(const float4*)(srcB + (size_t)j * (HW * HW))
                        : float4{0.f, 0.f, 0.f, 0.f};

        #pragma unroll
        for (int i = 0; i < 4; ++i) {
            const int wiA = 4 * qA - 3 + i;
            if (wiA >= 0 && wiA <= 65) {
                s16x8 pk;
                #pragma unroll
                for (int j = 0; j < 8; ++j) {
                    const float* vf = (const float*)&va[j];
                    pk[j] = (short)f2bf(vf[i]);
                }
                *(s16x8*)&feat_lds[rA][wiA][octA * 8] = pk;
            }
        }
        if (hasB) {
            #pragma unroll
            for (int i = 0; i < 4; ++i) {
                const int wiB = 4 * qB - 3 + i;
                if (wiB >= 0 && wiB <= 65) {
                    s16x8 pk;
                    #pragma unroll
                    for (int j = 0; j < 8; ++j) {
                        const float* vf = (const float*)&vb[j];
                        pk[j] = (short)f2bf(vf[i]);
                    }
                    *(s16x8*)&feat_lds[rB][wiB][octB * 8] = pk;
                }
            }
        }
    }

    // tm prefetch (independent of LDS; in flight across the barrier)
    float tmr[NTAP];
    #pragma unroll
    for (int t = 0; t < NTAP; ++t)
        tmr[t] = tm[((size_t)(b * NTAP + t)) * (HW * HW) + (size_t)h * HW + wout];

    __syncthreads();

    const s16x8* __restrict__ Wf8 = (const s16x8*)Wf;

    f32x16 acc = {0,0,0,0,0,0,0,0,0,0,0,0,0,0,0,0};

    __builtin_amdgcn_s_setprio(1);
    #pragma unroll
    for (int tap = 0; tap < NTAP; ++tap) {
        const int di = tap / 3;
        const int dj = tap % 3;
        const s16x8* bp = (const s16x8*)&feat_lds[di][pw + dj][0];
        f32x16 pa = {0,0,0,0,0,0,0,0,0,0,0,0,0,0,0,0};
        #pragma unroll
        for (int s = 0; s < 4; ++s) {
            s16x8 bf = bp[2 * s + g];                              // ds_read_b128
            s16x8 a  = Wf8[((tap * 4 + s) * 2 + m) * 64 + lane];   // L1/L2-hot
            pa = __builtin_amdgcn_mfma_f32_32x32x16_bf16(a, bf, pa, 0, 0, 0);
        }
        const float tv = tmr[tap];
        #pragma unroll
        for (int r = 0; r < 16; ++r)
            acc[r] = fmaf(tv, pa[r], acc[r]);
    }
    __builtin_amdgcn_s_setprio(0);

    // ---- store: D (32x32): col = c31 (pixel), o = (r&3)+8*(r>>2)+4*g+32*m ----
    float* op = out + ((size_t)b * O_DIM) * (HW * HW) + (size_t)h * HW + wout;
    #pragma unroll
    for (int r = 0; r < 16; ++r) {
        const int o = (r & 3) + ((r >> 2) << 3) + (g << 2) + (m << 5);
        op[(size_t)o * (HW * HW)] = acc[r];
    }
}

extern "C" void kernel_launch(void* const* d_in, const int* in_sizes, int n_in,
                              void* d_out, int out_size, void* d_ws, size_t ws_size,
                              hipStream_t stream) {
    const float* feat = (const float*)d_in[0];   // [8,64,128,128] f32
    const float* tm   = (const float*)d_in[1];   // [8,9,16384]    f32
    const float* W    = (const float*)d_in[2];   // [64,3,3,64]    f32
    float* out        = (float*)d_out;           // [8,64,128,128] f32
    unsigned short* Wf = (unsigned short*)d_ws;  // 73728 B scratch

    swizzle_W_kernel<<<dim3(144), dim3(256), 0, stream>>>(W, Wf);
    dyconv_kernel<<<dim3(2048), dim3(256), 0, stream>>>(feat, tm, Wf, out);
}

// Round 16
// 31.803 us; speedup vs baseline: 1.7489x; 1.1573x over previous
//
#include <hip/hip_runtime.h>

// Problem constants (B, C, O, K, H, W) = (8, 64, 64, 3, 128, 128)
#define NTAP 9
#define C_DIM 64
#define O_DIM 64
#define HW 128
#define CPAD 72   // LDS w-row stride 144B: 16B-aligned, 4-way worst-case banks

typedef short s16x8 __attribute__((ext_vector_type(8)));
typedef float f32x16 __attribute__((ext_vector_type(16)));

__device__ __forceinline__ unsigned short f2bf(float x) {
    unsigned int u = __float_as_uint(x);
    unsigned int r = (u + 0x7fffu + ((u >> 16) & 1u)) >> 16;
    return (unsigned short)r;
}

// ---------------------------------------------------------------------------
// Pre-kernel: W [C=64][3][3][O=64] f32 -> fragment-major bf16 (d_ws, 72KB).
// Fragment F = ((tap*4 + s)*2 + m)*64 + lane, element e:
//   c = 16*s + 8*(lane>>5) + e,   o = 32*m + (lane&31)
// Same (lane>>5, e) -> k-slot mapping is used for the feat (B) operand, so the
// contraction is correct under any hardware k-slot permutation.
// ---------------------------------------------------------------------------
__global__ void swizzle_W_kernel(const float* __restrict__ W,
                                 unsigned short* __restrict__ Wf) {
    int idx = blockIdx.x * 256 + threadIdx.x;
    if (idx >= NTAP * 4 * 2 * 64 * 8) return;
    int e    = idx & 7;
    int lane = (idx >> 3) & 63;
    int m    = (idx >> 9) & 1;
    int s    = (idx >> 10) & 3;
    int tap  = idx >> 12;
    int c = s * 16 + ((lane >> 5) << 3) + e;
    int o = (m << 5) + (lane & 31);
    Wf[idx] = f2bf(W[c * 576 + tap * 64 + o]);
}

// ---------------------------------------------------------------------------
// Main kernel: EXACT R8-champion structure (31.1us) + A-fragment ping-pong.
// One block per (batch, row h, 64-w half). 256 threads = 4 waves, grid 2048.
// LDS window: 3 rows x 66 w x 64 c bf16 (28.5KB, CPAD=72) -> 4 blocks/CU.
// Wave (m = o-half, pg = w-32-group): ONE 32px x 32o chain, 36 MFMA, tm fold.
// NEW: Abuf[2][4] double-buffer -- tap t+1's 4 A-fragments (16B global loads,
// L2-hot) are issued while tap t's MFMAs+fold execute; tap 0's fragments are
// issued BEFORE the barrier so they overlap the staging drain. Indices into
// Abuf are compile-time constants under the fully-unrolled tap loop.
// ---------------------------------------------------------------------------
__global__ __launch_bounds__(256, 4) void dyconv_kernel(
    const float* __restrict__ feat, const float* __restrict__ tm,
    const unsigned short* __restrict__ Wf, float* __restrict__ out)
{
    __shared__ __align__(16) unsigned short feat_lds[3][66][CPAD];

    // bijective XCD swizzle: XCD x gets batch x; h/w neighbors adjacent in time
    const int flat  = blockIdx.x;             // 0..2047
    const int b     = flat & 7;
    const int inner = flat >> 3;              // 0..255
    const int h     = inner >> 1;             // 0..127
    const int w0    = (inner & 1) << 6;       // 0 or 64

    const int tid = threadIdx.x;

    // ---- stage rows h-1..h+1, w-span [w0-4, w0+68) x 64 c (halos included) ----
    // unit U = ((r*8 + oct)*18 + q): float4 span load of 4 w x 8 c, pack to bf16
    for (int U = tid; U < 432; U += 256) {
        const int q   = U % 18;               // w-quad: wb = w0-4+4q
        const int ro  = U / 18;
        const int oct = ro & 7;               // c-octet: c0 = oct*8
        const int r   = ro >> 3;              // input row 0..2 (hr = h-1+r)
        const int hr  = h - 1 + r;
        const int wb  = w0 - 4 + 4 * q;
        const bool ld = (hr >= 0) && (hr < HW) && (wb >= 0) && (wb <= HW - 4);
        const float* src = feat + (((size_t)(b * C_DIM + oct * 8)) * HW + hr) * HW + wb;
        float4 v[8];
        #pragma unroll
        for (int j = 0; j < 8; ++j)
            v[j] = ld ? *(const float4*)(src + (size_t)j * (HW * HW))
                      : float4{0.f, 0.f, 0.f, 0.f};
        #pragma unroll
        for (int i = 0; i < 4; ++i) {
            const int wi = 4 * q - 3 + i;     // window index = w_in - (w0-1)
            if (wi >= 0 && wi <= 65) {
                s16x8 pk;
                #pragma unroll
                for (int j = 0; j < 8; ++j) {
                    const float* vf = (const float*)&v[j];
                    pk[j] = (short)f2bf(vf[i]);
                }
                *(s16x8*)&feat_lds[r][wi][oct * 8] = pk;
            }
        }
    }

    const int lane = tid & 63;
    const int wave = tid >> 6;                // 0..3
    const int m    = wave >> 1;               // o-half
    const int pg   = wave & 1;                // px 32-group within the 64-w tile
    const int g    = lane >> 5;               // k-slot half
    const int c31  = lane & 31;               // MFMA column = pixel index
    const int wout = w0 + pg * 32 + c31;

    // prefetch tm scalars (independent of LDS; in flight across the barrier)
    float tmr[NTAP];
    #pragma unroll
    for (int t = 0; t < NTAP; ++t)
        tmr[t] = tm[((size_t)(b * NTAP + t)) * (HW * HW) + (size_t)h * HW + wout];

    // A-fragment base for this (m, lane); frag (tap,s) at offset (tap*4+s)*128
    const s16x8* __restrict__ Wbase = (const s16x8*)Wf + (size_t)m * 64 + lane;

    // issue tap 0's A-fragments BEFORE the barrier (overlap staging drain)
    s16x8 Abuf[2][4];
    #pragma unroll
    for (int s = 0; s < 4; ++s)
        Abuf[0][s] = Wbase[s * 128];

    __syncthreads();

    f32x16 acc = {0,0,0,0,0,0,0,0,0,0,0,0,0,0,0,0};

    __builtin_amdgcn_s_setprio(1);
    #pragma unroll
    for (int tap = 0; tap < NTAP; ++tap) {
        const int cur = tap & 1;
        const int nxt = cur ^ 1;
        // prefetch next tap's A-fragments (in flight under this tap's MFMAs)
        if (tap < NTAP - 1) {
            #pragma unroll
            for (int s = 0; s < 4; ++s)
                Abuf[nxt][s] = Wbase[((tap + 1) * 4 + s) * 128];
        }
        const int di = tap / 3;
        const int dj = tap % 3;
        const s16x8* bp = (const s16x8*)&feat_lds[di][pg * 32 + c31 + dj][0];
        f32x16 pa = {0,0,0,0,0,0,0,0,0,0,0,0,0,0,0,0};
        #pragma unroll
        for (int s = 0; s < 4; ++s) {
            s16x8 bf = bp[2 * s + g];                              // ds_read_b128
            pa = __builtin_amdgcn_mfma_f32_32x32x16_bf16(Abuf[cur][s], bf, pa, 0, 0, 0);
        }
        const float tv = tmr[tap];
        #pragma unroll
        for (int r = 0; r < 16; ++r)
            acc[r] = fmaf(tv, pa[r], acc[r]);
    }
    __builtin_amdgcn_s_setprio(0);

    // ---- store: D (32x32): col = lane&31 (pixel), o = (r&3)+8*(r>>2)+4*g+32*m
    float* op = out + ((size_t)b * O_DIM) * (HW * HW) + (size_t)h * HW + wout;
    #pragma unroll
    for (int r = 0; r < 16; ++r) {
        const int o = (r & 3) + ((r >> 2) << 3) + (g << 2) + (m << 5);
        op[(size_t)o * (HW * HW)] = acc[r];
    }
}

extern "C" void kernel_launch(void* const* d_in, const int* in_sizes, int n_in,
                              void* d_out, int out_size, void* d_ws, size_t ws_size,
                              hipStream_t stream) {
    const float* feat = (const float*)d_in[0];   // [8,64,128,128] f32
    const float* tm   = (const float*)d_in[1];   // [8,9,16384]    f32
    const float* W    = (const float*)d_in[2];   // [64,3,3,64]    f32
    float* out        = (float*)d_out;           // [8,64,128,128] f32
    unsigned short* Wf = (unsigned short*)d_ws;  // 73728 B scratch

    swizzle_W_kernel<<<dim3(144), dim3(256), 0, stream>>>(W, Wf);
    dyconv_kernel<<<dim3(2048), dim3(256), 0, stream>>>(feat, tm, Wf, out);
}